// Round 1
// baseline (343.531 us; speedup 1.0000x reference)
//
#include <hip/hip_runtime.h>

namespace {

constexpr int B  = 16;
constexpr int D  = 128;
constexpr int C  = 6;
constexpr int H  = 128;
constexpr int W  = 128;
constexpr int HWC = H * W;          // 16384
constexpr int HO = 512, WO = 512;   // 4x upsample

// ---------------------------------------------------------------------------
// K1: per-pixel argmax over C of (assp . cls_w + cls_b)  -> mask, counts
// one thread per pixel, d-loop with coalesced loads across hw
// ---------------------------------------------------------------------------
__global__ void k_mask_counts(const float* __restrict__ assp,
                              const float* __restrict__ cls_w,
                              const float* __restrict__ cls_b,
                              unsigned char* __restrict__ mask,
                              int* __restrict__ counts) {
  __shared__ float ws[C * D];
  __shared__ float bs[C];
  __shared__ int   cs[C];
  int tid = threadIdx.x;
  for (int i = tid; i < C * D; i += 256) ws[i] = cls_w[i];
  if (tid < C) { bs[tid] = cls_b[tid]; cs[tid] = 0; }
  __syncthreads();

  int p  = blockIdx.x * 256 + tid;        // global pixel id, b*HWC + hw
  int b  = p >> 14;
  int hw = p & (HWC - 1);
  const float* base = assp + ((size_t)b * D) * HWC + hw;

  float a0 = 0.f, a1 = 0.f, a2 = 0.f, a3 = 0.f, a4 = 0.f, a5 = 0.f;
#pragma unroll 4
  for (int d = 0; d < D; ++d) {
    float v = base[(size_t)d * HWC];
    a0 += v * ws[0 * D + d];
    a1 += v * ws[1 * D + d];
    a2 += v * ws[2 * D + d];
    a3 += v * ws[3 * D + d];
    a4 += v * ws[4 * D + d];
    a5 += v * ws[5 * D + d];
  }
  a0 += bs[0]; a1 += bs[1]; a2 += bs[2]; a3 += bs[3]; a4 += bs[4]; a5 += bs[5];

  int best = 0; float bv = a0;             // first-wins ties == jnp.argmax
  if (a1 > bv) { bv = a1; best = 1; }
  if (a2 > bv) { bv = a2; best = 2; }
  if (a3 > bv) { bv = a3; best = 3; }
  if (a4 > bv) { bv = a4; best = 4; }
  if (a5 > bv) { bv = a5; best = 5; }

  mask[p] = (unsigned char)best;
  atomicAdd(&cs[best], 1);
  __syncthreads();
  if (tid < C) atomicAdd(&counts[b * C + tid], cs[tid]);
}

// ---------------------------------------------------------------------------
// K2: per-class feature sums -> protoC[b,c,d] = sum/(cnt+1e-5), 0 if cnt==0
// one block per (b,d): no atomics, clean ownership
// ---------------------------------------------------------------------------
__global__ void k_proto(const float* __restrict__ assp,
                        const unsigned char* __restrict__ mask,
                        const int* __restrict__ counts,
                        float* __restrict__ protoC) {
  int d = blockIdx.x;
  int b = blockIdx.y;
  int tid = threadIdx.x;                   // 256 threads
  const float* base = assp + ((size_t)b * D + d) * HWC;
  const unsigned char* mb = mask + (size_t)b * HWC;

  float a0 = 0.f, a1 = 0.f, a2 = 0.f, a3 = 0.f, a4 = 0.f, a5 = 0.f;
  for (int hw = tid; hw < HWC; hw += 256) {
    float v = base[hw];
    int   m = mb[hw];
    a0 += (m == 0) ? v : 0.f;
    a1 += (m == 1) ? v : 0.f;
    a2 += (m == 2) ? v : 0.f;
    a3 += (m == 3) ? v : 0.f;
    a4 += (m == 4) ? v : 0.f;
    a5 += (m == 5) ? v : 0.f;
  }
  // wave reduce (64-wide), then cross-wave via LDS
#pragma unroll
  for (int off = 32; off >= 1; off >>= 1) {
    a0 += __shfl_xor(a0, off, 64);
    a1 += __shfl_xor(a1, off, 64);
    a2 += __shfl_xor(a2, off, 64);
    a3 += __shfl_xor(a3, off, 64);
    a4 += __shfl_xor(a4, off, 64);
    a5 += __shfl_xor(a5, off, 64);
  }
  __shared__ float red[C][4];
  int lane = tid & 63, wv = tid >> 6;
  if (lane == 0) {
    red[0][wv] = a0; red[1][wv] = a1; red[2][wv] = a2;
    red[3][wv] = a3; red[4][wv] = a4; red[5][wv] = a5;
  }
  __syncthreads();
  if (tid < C) {
    float s = red[tid][0] + red[tid][1] + red[tid][2] + red[tid][3];
    float cnt = (float)counts[b * C + tid];
    float pv = (cnt > 0.f) ? s / (cnt + 1e-5f) : 0.f;
    protoC[((size_t)b * C + tid) * D + d] = pv;
  }
}

// ---------------------------------------------------------------------------
// K3: replace the P listed pixels with their nearest prototype (in place).
// one wave per (b,p); lane owns d and d+64
// ---------------------------------------------------------------------------
__global__ void k_replace(float* __restrict__ assp,
                          const float* __restrict__ protoC,
                          const int* __restrict__ px,
                          const int* __restrict__ py,
                          int P) {
  int bp = blockIdx.x;
  int b = bp / P, p = bp % P;
  int hw = px[p] * W + py[p];
  int lane = threadIdx.x;                  // 64 threads = 1 wave
  float* base = assp + ((size_t)b * D) * HWC + hw;
  const float* pr = protoC + (size_t)b * C * D;

  float f0 = base[(size_t)lane * HWC];
  float f1 = base[(size_t)(lane + 64) * HWC];

  float ds[C];
#pragma unroll
  for (int c = 0; c < C; ++c) {
    float d0 = pr[c * D + lane]      - f0;
    float d1 = pr[c * D + lane + 64] - f1;
    float s = d0 * d0 + d1 * d1;
#pragma unroll
    for (int off = 32; off >= 1; off >>= 1) s += __shfl_xor(s, off, 64);
    ds[c] = s;                             // same value on all lanes
  }
  int best = 0; float bv = ds[0];          // first-wins ties == jnp.argmin
#pragma unroll
  for (int c = 1; c < C; ++c)
    if (ds[c] < bv) { bv = ds[c]; best = c; }

  base[(size_t)lane * HWC]        = pr[best * D + lane];
  base[(size_t)(lane + 64) * HWC] = pr[best * D + lane + 64];
}

// ---------------------------------------------------------------------------
// K4: x[b,c,hw] = dot(assp'[b,:,hw], cls_w[c,:]) / 12 + cls_b[c]
// (softmax(...,axis=1).mean(axis=1) == 1/12 identically -> attention is dead)
// ---------------------------------------------------------------------------
__global__ void k_x(const float* __restrict__ assp,
                    const float* __restrict__ cls_w,
                    const float* __restrict__ cls_b,
                    float* __restrict__ x) {
  __shared__ float ws[C * D];
  __shared__ float bs[C];
  int tid = threadIdx.x;
  for (int i = tid; i < C * D; i += 256) ws[i] = cls_w[i];
  if (tid < C) bs[tid] = cls_b[tid];
  __syncthreads();

  int p  = blockIdx.x * 256 + tid;
  int b  = p >> 14;
  int hw = p & (HWC - 1);
  const float* base = assp + ((size_t)b * D) * HWC + hw;

  float a0 = 0.f, a1 = 0.f, a2 = 0.f, a3 = 0.f, a4 = 0.f, a5 = 0.f;
#pragma unroll 4
  for (int d = 0; d < D; ++d) {
    float v = base[(size_t)d * HWC];
    a0 += v * ws[0 * D + d];
    a1 += v * ws[1 * D + d];
    a2 += v * ws[2 * D + d];
    a3 += v * ws[3 * D + d];
    a4 += v * ws[4 * D + d];
    a5 += v * ws[5 * D + d];
  }
  const float inv12 = 1.0f / 12.0f;
  float* xb = x + ((size_t)b * C) * HWC + hw;
  xb[0 * HWC] = a0 * inv12 + bs[0];
  xb[1 * HWC] = a1 * inv12 + bs[1];
  xb[2 * HWC] = a2 * inv12 + bs[2];
  xb[3 * HWC] = a3 * inv12 + bs[3];
  xb[4 * HWC] = a4 * inv12 + bs[4];
  xb[5 * HWC] = a5 * inv12 + bs[5];
}

// ---------------------------------------------------------------------------
// K5: bilinear 4x upsample with numpy-matched weights:
// src = (i*127)/511 in double, lo = floor, w = float(src-lo)
// ---------------------------------------------------------------------------
__global__ void k_up(const float* __restrict__ x, float* __restrict__ out) {
  int i = blockIdx.x * 256 + threadIdx.x;        // < 16*6*512*512 = 25,165,824
  int X  = i & (WO - 1);
  int Y  = (i >> 9) & (HO - 1);
  int bc = i >> 18;

  double sy = (double)(Y * (H - 1)) / (double)(HO - 1);
  int y0 = (int)sy;
  float wy = (float)(sy - (double)y0);
  int y1 = y0 + 1; if (y1 > H - 1) y1 = H - 1;

  double sx = (double)(X * (W - 1)) / (double)(WO - 1);
  int x0 = (int)sx;
  float wx = (float)(sx - (double)x0);
  int x1 = x0 + 1; if (x1 > W - 1) x1 = W - 1;

  const float* xb = x + (size_t)bc * HWC;
  float v00 = xb[y0 * W + x0];
  float v01 = xb[y0 * W + x1];
  float v10 = xb[y1 * W + x0];
  float v11 = xb[y1 * W + x1];

  float r = (1.f - wy) * ((1.f - wx) * v00 + wx * v01)
          +        wy  * ((1.f - wx) * v10 + wx * v11);
  out[i] = r;
}

} // namespace

extern "C" void kernel_launch(void* const* d_in, const int* in_sizes, int n_in,
                              void* d_out, int out_size, void* d_ws, size_t ws_size,
                              hipStream_t stream) {
  // inputs: assp, cls_w, cls_b, key_w, key_b, query_w, query_b, px, py
  float*       assp  = (float*)d_in[0];   // modified in place; harness restores
  const float* cls_w = (const float*)d_in[1];
  const float* cls_b = (const float*)d_in[2];
  const int*   px    = (const int*)d_in[7];
  const int*   py    = (const int*)d_in[8];
  const int    P     = in_sizes[7];       // 102

  // workspace layout (~6.6 MB total)
  char* ws = (char*)d_ws;
  unsigned char* mask   = (unsigned char*)ws;                   // 262144 B
  int*           counts = (int*)(ws + 262144);                  // 384 B
  float*         protoC = (float*)(ws + 262144 + 512);          // 49152 B
  float*         x      = (float*)(ws + 262144 + 512 + 49152);  // 6 MB

  float* out = (float*)d_out;

  hipMemsetAsync(counts, 0, B * C * sizeof(int), stream);
  k_mask_counts<<<B * HWC / 256, 256, 0, stream>>>(assp, cls_w, cls_b, mask, counts);
  k_proto<<<dim3(D, B), 256, 0, stream>>>(assp, mask, counts, protoC);
  k_replace<<<B * P, 64, 0, stream>>>(assp, protoC, px, py, P);
  k_x<<<B * HWC / 256, 256, 0, stream>>>(assp, cls_w, cls_b, x);
  k_up<<<(B * C * HO * WO) / 256, 256, 0, stream>>>(x, out);
}

// Round 2
// 293.927 us; speedup vs baseline: 1.1688x; 1.1688x over previous
//
#include <hip/hip_runtime.h>

namespace {

constexpr int B  = 16;
constexpr int D  = 128;
constexpr int C  = 6;
constexpr int H  = 128;
constexpr int W  = 128;
constexpr int HWC = H * W;          // 16384
constexpr int HO = 512, WO = 512;   // 4x upsample

// ---------------------------------------------------------------------------
// K1: per-pixel dots d.cls_w -> mask (argmax) AND x = dot/12 + bias
// (softmax(...,axis=1).mean(axis=1) == 1/12 identically -> attention branch
//  is dead code; x only needs the classifier dots)
// float2 per thread: 512 blocks -> 2 blocks/CU, unroll-8 keeps loads in flight
// ---------------------------------------------------------------------------
__global__ void k_mask_x(const float* __restrict__ assp,
                         const float* __restrict__ cls_w,
                         const float* __restrict__ cls_b,
                         unsigned char* __restrict__ mask,
                         float* __restrict__ x) {
  __shared__ float ws[C * D];
  __shared__ float bs[C];
  int tid = threadIdx.x;
  for (int i = tid; i < C * D; i += 256) ws[i] = cls_w[i];
  if (tid < C) bs[tid] = cls_b[tid];
  __syncthreads();

  int p2 = (blockIdx.x * 256 + tid) * 2;   // 2 consecutive pixels, same b
  int b  = p2 >> 14;
  int hw = p2 & (HWC - 1);
  const float* base = assp + ((size_t)b * D) * HWC + hw;

  float acc[C][2];
#pragma unroll
  for (int c = 0; c < C; ++c) { acc[c][0] = 0.f; acc[c][1] = 0.f; }

#pragma unroll 8
  for (int d = 0; d < D; ++d) {
    const float2 v = *(const float2*)(base + (size_t)d * HWC);
#pragma unroll
    for (int c = 0; c < C; ++c) {
      float w = ws[c * D + d];
      acc[c][0] += v.x * w;
      acc[c][1] += v.y * w;
    }
  }

  unsigned char mv[2];
#pragma unroll
  for (int j = 0; j < 2; ++j) {
    float bv = acc[0][j] + bs[0]; int best = 0;   // first-wins == jnp.argmax
#pragma unroll
    for (int c = 1; c < C; ++c) {
      float v = acc[c][j] + bs[c];
      if (v > bv) { bv = v; best = c; }
    }
    mv[j] = (unsigned char)best;
  }
  uchar2 m2; m2.x = mv[0]; m2.y = mv[1];
  *(uchar2*)(mask + p2) = m2;

  const float inv12 = 1.0f / 12.0f;
  float* xb = x + ((size_t)b * C) * HWC + hw;
#pragma unroll
  for (int c = 0; c < C; ++c) {
    float2 o;
    o.x = acc[c][0] * inv12 + bs[c];
    o.y = acc[c][1] * inv12 + bs[c];
    *(float2*)(xb + (size_t)c * HWC) = o;
  }
}

// ---------------------------------------------------------------------------
// K2: protoC[b,c,d] = sum_{mask==c} assp / (cnt+1e-5); counts derived locally
// (no global counts buffer, no atomics, no memset dispatch)
// one block per (b,d); float4 + uchar4 loads
// ---------------------------------------------------------------------------
__global__ void k_proto(const float* __restrict__ assp,
                        const unsigned char* __restrict__ mask,
                        float* __restrict__ protoC) {
  int d = blockIdx.x;
  int b = blockIdx.y;
  int tid = threadIdx.x;                   // 256 threads
  const float* base = assp + ((size_t)b * D + d) * HWC;
  const unsigned char* mb = mask + (size_t)b * HWC;

  float s[C]  = {0.f, 0.f, 0.f, 0.f, 0.f, 0.f};
  int   cn[C] = {0, 0, 0, 0, 0, 0};
  for (int hw = tid * 4; hw < HWC; hw += 256 * 4) {
    float4 v = *(const float4*)(base + hw);
    uchar4 m = *(const uchar4*)(mb + hw);
#pragma unroll
    for (int c = 0; c < C; ++c) {
      bool e0 = (m.x == c), e1 = (m.y == c), e2 = (m.z == c), e3 = (m.w == c);
      s[c] += (e0 ? v.x : 0.f) + (e1 ? v.y : 0.f)
            + (e2 ? v.z : 0.f) + (e3 ? v.w : 0.f);
      cn[c] += (int)e0 + (int)e1 + (int)e2 + (int)e3;
    }
  }

  float cf[C];
#pragma unroll
  for (int c = 0; c < C; ++c) cf[c] = (float)cn[c];
#pragma unroll
  for (int off = 32; off >= 1; off >>= 1) {
#pragma unroll
    for (int c = 0; c < C; ++c) {
      s[c]  += __shfl_xor(s[c],  off, 64);
      cf[c] += __shfl_xor(cf[c], off, 64);
    }
  }
  __shared__ float red_s[C][4];
  __shared__ float red_c[C][4];
  int lane = tid & 63, wv = tid >> 6;
  if (lane == 0) {
#pragma unroll
    for (int c = 0; c < C; ++c) { red_s[c][wv] = s[c]; red_c[c][wv] = cf[c]; }
  }
  __syncthreads();
  if (tid < C) {
    float sum = red_s[tid][0] + red_s[tid][1] + red_s[tid][2] + red_s[tid][3];
    float cnt = red_c[tid][0] + red_c[tid][1] + red_c[tid][2] + red_c[tid][3];
    float pv = (cnt > 0.f) ? sum / (cnt + 1e-5f) : 0.f;
    protoC[((size_t)b * C + tid) * D + d] = pv;
  }
}

// ---------------------------------------------------------------------------
// K3: for each dropped pixel: nearest proto (L2, first-wins over the 12=2x6
// duplicated list -> same as over 6), then PATCH x directly:
// x[b,:,px,py] = (proto_best . cls_w)/12 + cls_b.  assp itself never written.
// one wave per (b,p); lane owns d and d+64
// ---------------------------------------------------------------------------
__global__ void k_replace_patch(const float* __restrict__ assp,
                                const float* __restrict__ protoC,
                                const float* __restrict__ cls_w,
                                const float* __restrict__ cls_b,
                                const int* __restrict__ px,
                                const int* __restrict__ py,
                                int P,
                                float* __restrict__ x) {
  int bp = blockIdx.x;
  int b = bp / P, p = bp % P;
  int hw = px[p] * W + py[p];
  int lane = threadIdx.x;                  // 64 threads = 1 wave
  const float* fbase = assp + ((size_t)b * D) * HWC + hw;
  const float* pr = protoC + (size_t)b * C * D;

  float f0 = fbase[(size_t)lane * HWC];
  float f1 = fbase[(size_t)(lane + 64) * HWC];

  float ds[C];
#pragma unroll
  for (int c = 0; c < C; ++c) {
    float d0 = pr[c * D + lane]      - f0;
    float d1 = pr[c * D + lane + 64] - f1;
    float t = d0 * d0 + d1 * d1;
#pragma unroll
    for (int off = 32; off >= 1; off >>= 1) t += __shfl_xor(t, off, 64);
    ds[c] = t;                             // identical on all lanes
  }
  int best = 0; float bv = ds[0];          // first-wins ties == jnp.argmin
#pragma unroll
  for (int c = 1; c < C; ++c)
    if (ds[c] < bv) { bv = ds[c]; best = c; }

  float v0 = pr[best * D + lane];
  float v1 = pr[best * D + lane + 64];

  float myx = 0.f;
#pragma unroll
  for (int c = 0; c < C; ++c) {
    float t = v0 * cls_w[c * D + lane] + v1 * cls_w[c * D + lane + 64];
#pragma unroll
    for (int off = 32; off >= 1; off >>= 1) t += __shfl_xor(t, off, 64);
    float val = t * (1.0f / 12.0f) + cls_b[c];
    if (lane == c) myx = val;
  }
  if (lane < C) x[((size_t)b * C + lane) * HWC + hw] = myx;
}

// ---------------------------------------------------------------------------
// K4: bilinear 4x upsample, numpy-matched weights (src = i*127/511 in double),
// 4 outputs / thread, float4 store
// ---------------------------------------------------------------------------
__global__ void k_up(const float* __restrict__ x, float* __restrict__ out) {
  int t = blockIdx.x * 256 + threadIdx.x;
  int i = t * 4;                               // 4 consecutive X, same row
  int X  = i & (WO - 1);
  int Y  = (i >> 9) & (HO - 1);
  int bc = i >> 18;

  double sy = (double)(Y * (H - 1)) / (double)(HO - 1);
  int y0 = (int)sy;
  float wy = (float)(sy - (double)y0);
  int y1 = y0 + 1; if (y1 > H - 1) y1 = H - 1;

  const float* r0 = x + (size_t)bc * HWC + y0 * W;
  const float* r1 = x + (size_t)bc * HWC + y1 * W;

  float o[4];
#pragma unroll
  for (int j = 0; j < 4; ++j) {
    int Xj = X + j;
    double sx = (double)(Xj * (W - 1)) / (double)(WO - 1);
    int x0 = (int)sx;
    float wx = (float)(sx - (double)x0);
    int x1 = x0 + 1; if (x1 > W - 1) x1 = W - 1;

    float v00 = r0[x0], v01 = r0[x1], v10 = r1[x0], v11 = r1[x1];
    o[j] = (1.f - wy) * ((1.f - wx) * v00 + wx * v01)
         +        wy  * ((1.f - wx) * v10 + wx * v11);
  }
  float4 o4; o4.x = o[0]; o4.y = o[1]; o4.z = o[2]; o4.w = o[3];
  *(float4*)(out + i) = o4;
}

} // namespace

extern "C" void kernel_launch(void* const* d_in, const int* in_sizes, int n_in,
                              void* d_out, int out_size, void* d_ws, size_t ws_size,
                              hipStream_t stream) {
  // inputs: assp, cls_w, cls_b, key_w, key_b, query_w, query_b, px, py
  const float* assp  = (const float*)d_in[0];   // read-only now
  const float* cls_w = (const float*)d_in[1];
  const float* cls_b = (const float*)d_in[2];
  const int*   px    = (const int*)d_in[7];
  const int*   py    = (const int*)d_in[8];
  const int    P     = in_sizes[7];             // 102

  // workspace layout (~6.3 MB)
  char* ws = (char*)d_ws;
  unsigned char* mask   = (unsigned char*)ws;                   // 262144 B
  float*         protoC = (float*)(ws + 262144);                // 49152 B
  float*         x      = (float*)(ws + 262144 + 49152);        // 6 MB

  float* out = (float*)d_out;

  k_mask_x<<<B * HWC / 512, 256, 0, stream>>>(assp, cls_w, cls_b, mask, x);
  k_proto<<<dim3(D, B), 256, 0, stream>>>(assp, mask, protoC);
  k_replace_patch<<<B * P, 64, 0, stream>>>(assp, protoC, cls_w, cls_b, px, py, P, x);
  k_up<<<(B * C * HO * WO) / 1024, 256, 0, stream>>>(x, out);
}

// Round 3
// 277.087 us; speedup vs baseline: 1.2398x; 1.0608x over previous
//
#include <hip/hip_runtime.h>

namespace {

constexpr int B  = 16;
constexpr int D  = 128;
constexpr int C  = 6;
constexpr int H  = 128;
constexpr int W  = 128;
constexpr int HWC = H * W;          // 16384
constexpr int HO = 512, WO = 512;   // 4x upsample
constexpr int TILE = 64;            // pixels per LDS tile
constexpr int TPB  = 8;             // tiles per block (block owns 512 contiguous px)

// ---------------------------------------------------------------------------
// Fused K1+K2: one HBM pass over assp.
// Per 64-px tile staged in LDS (XOR-swizzled, conflict-free both ways):
//   2a: px-ownership dots -> argmax class (register mask) + x = dot/12 + b
//   2b: d-ownership per-class sums, accumulated in registers across 8 tiles
// Block-end: pair-reduce + global atomicAdd into sums[B][C][D], counts[B][C].
// (softmax(...,axis=1).mean(axis=1) == 1/12 -> attention branch is dead code)
// ---------------------------------------------------------------------------
__global__ __launch_bounds__(256) void k_fused(const float* __restrict__ assp,
                                               const float* __restrict__ cls_w,
                                               const float* __restrict__ cls_b,
                                               float* __restrict__ sums,
                                               int* __restrict__ counts,
                                               float* __restrict__ x) {
  __shared__ float tile[D * TILE];      // [d*64 + (px ^ (d&62))], 32 KB
  __shared__ float red[4 * C * TILE];   // red[q][c][px], 6 KB (reused as part[])
  __shared__ float ws[C * D];
  __shared__ float bs[C];

  const int t  = threadIdx.x;
  const int b  = blockIdx.y;
  for (int i = t; i < C * D; i += 256) ws[i] = cls_w[i];
  if (t < C) bs[t] = cls_b[t];

  const int lane = t & 63;
  const int wv   = t >> 6;        // quarter for 2a, wave id
  const int d2b  = t & 127;       // d owned in 2b
  const int h2b  = t >> 7;        // px-half owned in 2b
  const int d1   = t >> 5;        // base d row for staging
  const int px2  = (t & 31) * 2;  // px pair for staging

  float acc2b[C] = {0.f, 0.f, 0.f, 0.f, 0.f, 0.f};
  int   cnt_run  = 0;             // wave0 lane c accumulates count of class c

  __syncthreads();                // ws/bs ready

  for (int it = 0; it < TPB; ++it) {
    const int hw0 = (blockIdx.x * TPB + it) * TILE;
    const float* base = assp + ((size_t)b * D) * HWC + hw0;

    // ---- phase 1: global -> LDS (swizzled), 16 independent float2 loads ----
    float2 v[16];
#pragma unroll
    for (int j = 0; j < 16; ++j) {
      int d = d1 + 8 * j;
      v[j] = *(const float2*)(base + (size_t)d * HWC + px2);
    }
#pragma unroll
    for (int j = 0; j < 16; ++j) {
      int d = d1 + 8 * j;
      *(float2*)&tile[d * TILE + (px2 ^ (d & 62))] = v[j];
    }
    __syncthreads();

    // ---- phase 2a: dots (px = lane, d-quarter = wv) ----
    {
      float a[C] = {0.f, 0.f, 0.f, 0.f, 0.f, 0.f};
#pragma unroll
      for (int dd = 0; dd < 32; ++dd) {
        int d = wv * 32 + dd;
        float vv = tile[d * TILE + (lane ^ (d & 62))];
#pragma unroll
        for (int c = 0; c < C; ++c) a[c] += vv * ws[c * D + d];
      }
#pragma unroll
      for (int c = 0; c < C; ++c) red[(wv * C + c) * TILE + lane] = a[c];
    }
    __syncthreads();

    // ---- finalize (replicated in all waves): class of px = lane ----
    int cls;
    {
      float s[C];
#pragma unroll
      for (int c = 0; c < C; ++c)
        s[c] = red[(0 * C + c) * TILE + lane] + red[(1 * C + c) * TILE + lane]
             + red[(2 * C + c) * TILE + lane] + red[(3 * C + c) * TILE + lane];
      float bv = s[0] + bs[0]; cls = 0;      // first-wins == jnp.argmax
#pragma unroll
      for (int c = 1; c < C; ++c) {
        float pv = s[c] + bs[c];
        if (pv > bv) { bv = pv; cls = c; }
      }
      if (wv == 0) {
        const float inv12 = 1.0f / 12.0f;
        float* xb = x + ((size_t)b * C) * HWC + hw0 + lane;
#pragma unroll
        for (int c = 0; c < C; ++c) xb[(size_t)c * HWC] = s[c] * inv12 + bs[c];
#pragma unroll
        for (int c = 0; c < C; ++c) {
          unsigned long long m = __ballot(cls == c);
          if (lane == c) cnt_run += (int)__popcll(m);
        }
      }
    }

    // ---- phase 2b: per-class sums (d = d2b, px-half = h2b) ----
#pragma unroll
    for (int i = 0; i < 32; ++i) {
      int px = h2b * 32 + i;
      float vv = tile[d2b * TILE + (px ^ (d2b & 62))];
      int c = __shfl(cls, px, 64);           // broadcast: all lanes hold cls(px=lane)
#pragma unroll
      for (int cc = 0; cc < C; ++cc) acc2b[cc] += (c == cc) ? vv : 0.f;
    }
    __syncthreads();                          // before next tile overwrites LDS
  }

  // ---- block epilogue: pair-reduce h halves, one atomic burst per block ----
  float* part = red;                          // reuse (>=768 floats)
  if (h2b == 1) {
#pragma unroll
    for (int c = 0; c < C; ++c) part[c * D + d2b] = acc2b[c];
  }
  __syncthreads();
  if (h2b == 0) {
#pragma unroll
    for (int c = 0; c < C; ++c) {
      float s = acc2b[c] + part[c * D + d2b];
      atomicAdd(&sums[((size_t)b * C + c) * D + d2b], s);
    }
  }
  if (wv == 0 && lane < C) atomicAdd(&counts[b * C + lane], cnt_run);
}

// ---------------------------------------------------------------------------
// K3: per dropped pixel: protoC on the fly from sums/counts, nearest proto
// (first-wins argmin == over the 12=2x6 duplicated list), patch x directly.
// one wave per (b,p); lane owns d and d+64
// ---------------------------------------------------------------------------
__global__ void k_patch(const float* __restrict__ assp,
                        const float* __restrict__ sums,
                        const int* __restrict__ counts,
                        const float* __restrict__ cls_w,
                        const float* __restrict__ cls_b,
                        const int* __restrict__ px,
                        const int* __restrict__ py,
                        int P,
                        float* __restrict__ x) {
  int bp = blockIdx.x;
  int b = bp / P, p = bp % P;
  int hw = px[p] * W + py[p];
  int lane = threadIdx.x;                  // 64 threads = 1 wave
  const float* fbase = assp + ((size_t)b * D) * HWC + hw;

  float f0 = fbase[(size_t)lane * HWC];
  float f1 = fbase[(size_t)(lane + 64) * HWC];

  float pv0[C], pv1[C], ds[C];
#pragma unroll
  for (int c = 0; c < C; ++c) {
    float cnt = (float)counts[b * C + c];
    float s0 = sums[((size_t)b * C + c) * D + lane];
    float s1 = sums[((size_t)b * C + c) * D + lane + 64];
    float q0 = (cnt > 0.f) ? s0 / (cnt + 1e-5f) : 0.f;
    float q1 = (cnt > 0.f) ? s1 / (cnt + 1e-5f) : 0.f;
    pv0[c] = q0; pv1[c] = q1;
    float e0 = q0 - f0, e1 = q1 - f1;
    float tt = e0 * e0 + e1 * e1;
#pragma unroll
    for (int off = 32; off >= 1; off >>= 1) tt += __shfl_xor(tt, off, 64);
    ds[c] = tt;                            // identical on all lanes
  }
  int best = 0; float bv = ds[0];          // first-wins ties == jnp.argmin
#pragma unroll
  for (int c = 1; c < C; ++c)
    if (ds[c] < bv) { bv = ds[c]; best = c; }

  float v0 = 0.f, v1 = 0.f;                // select without dynamic indexing
#pragma unroll
  for (int c = 0; c < C; ++c) {
    if (best == c) { v0 = pv0[c]; v1 = pv1[c]; }
  }

  float myx = 0.f;
#pragma unroll
  for (int c = 0; c < C; ++c) {
    float tt = v0 * cls_w[c * D + lane] + v1 * cls_w[c * D + lane + 64];
#pragma unroll
    for (int off = 32; off >= 1; off >>= 1) tt += __shfl_xor(tt, off, 64);
    float val = tt * (1.0f / 12.0f) + cls_b[c];
    if (lane == c) myx = val;
  }
  if (lane < C) x[((size_t)b * C + lane) * HWC + hw] = myx;
}

// ---------------------------------------------------------------------------
// K4: bilinear 4x upsample, numpy-matched weights (src = i*127/511 in double),
// 4 outputs / thread, float4 store
// ---------------------------------------------------------------------------
__global__ void k_up(const float* __restrict__ x, float* __restrict__ out) {
  int t = blockIdx.x * 256 + threadIdx.x;
  int i = t * 4;                               // 4 consecutive X, same row
  int X  = i & (WO - 1);
  int Y  = (i >> 9) & (HO - 1);
  int bc = i >> 18;

  double sy = (double)(Y * (H - 1)) / (double)(HO - 1);
  int y0 = (int)sy;
  float wy = (float)(sy - (double)y0);
  int y1 = y0 + 1; if (y1 > H - 1) y1 = H - 1;

  const float* r0 = x + (size_t)bc * HWC + y0 * W;
  const float* r1 = x + (size_t)bc * HWC + y1 * W;

  float o[4];
#pragma unroll
  for (int j = 0; j < 4; ++j) {
    int Xj = X + j;
    double sx = (double)(Xj * (W - 1)) / (double)(WO - 1);
    int x0 = (int)sx;
    float wx = (float)(sx - (double)x0);
    int x1 = x0 + 1; if (x1 > W - 1) x1 = W - 1;

    float v00 = r0[x0], v01 = r0[x1], v10 = r1[x0], v11 = r1[x1];
    o[j] = (1.f - wy) * ((1.f - wx) * v00 + wx * v01)
         +        wy  * ((1.f - wx) * v10 + wx * v11);
  }
  float4 o4; o4.x = o[0]; o4.y = o[1]; o4.z = o[2]; o4.w = o[3];
  *(float4*)(out + i) = o4;
}

} // namespace

extern "C" void kernel_launch(void* const* d_in, const int* in_sizes, int n_in,
                              void* d_out, int out_size, void* d_ws, size_t ws_size,
                              hipStream_t stream) {
  // inputs: assp, cls_w, cls_b, key_w, key_b, query_w, query_b, px, py
  const float* assp  = (const float*)d_in[0];
  const float* cls_w = (const float*)d_in[1];
  const float* cls_b = (const float*)d_in[2];
  const int*   px    = (const int*)d_in[7];
  const int*   py    = (const int*)d_in[8];
  const int    P     = in_sizes[7];             // 102

  // workspace layout
  char* ws = (char*)d_ws;
  float* sums   = (float*)ws;                   // B*C*D = 49152 B
  int*   counts = (int*)(ws + 49152);           // B*C*4 = 384 B
  float* x      = (float*)(ws + 65536);         // B*C*HWC = 6 MB

  float* out = (float*)d_out;

  hipMemsetAsync(ws, 0, 49152 + 384, stream);
  k_fused<<<dim3(HWC / (TILE * TPB), B), 256, 0, stream>>>(assp, cls_w, cls_b,
                                                           sums, counts, x);
  k_patch<<<B * P, 64, 0, stream>>>(assp, sums, counts, cls_w, cls_b, px, py, P, x);
  k_up<<<(B * C * HO * WO) / 1024, 256, 0, stream>>>(x, out);
}